// Round 12
// baseline (105.117 us; speedup 1.0000x reference)
//
#include <hip/hip_runtime.h>
#include <hip/hip_bf16.h>
#include <math.h>

typedef __hip_bfloat16 bf16;
typedef float4 f4;

#define B 32
#define V 64
#define F 128
#define NL 128
#define H 8
#define DH 16
#define LEN_PRED 30

// ---- f32 workspace layout (element offsets) ----
#define WEMBW 0        // 768
#define WEMBB 768      // 128
#define WB1   896      // 128
#define WB2   1024     // 128
#define WBO   1152     // 36 (pad to 1192)
#define WPOS  1192     // 4096
// transposed [k][out]
#define WCP_T  5288    // 16384
#define WCSA_T 21672
#define WCLA_T 38056
#define W1_T   54440
#define W2_T   70824
#define WO_T   87208   // 4608 [k][36]
#define OFF_FEAT1 91904
#define OFF_FEAT2 354048
#define OFF_OSA1  616192
#define OFF_OSA2  878336

struct InPtrs { const void* p[23]; };

__device__ __forceinline__ float dot4(f4 a, f4 b) {
    return a.x * b.x + a.y * b.y + a.z * b.z + a.w * b.w;
}

// dtype detect: f32 read as u16 pairs has wild exponents in mantissa halves;
// bf16 N(0,1) never does. Uniform across all waves.
__device__ __forceinline__ int detect_f32(const void* lanesraw, int t) {
    const unsigned short* u = (const unsigned short*)lanesraw;
    int lane = t & 63;
    int wild = 0;
    for (int j = 0; j < 4; j++) {
        int e = (u[lane * 4 + j] >> 7) & 0xFF;
        if (e != 0 && (e < 90 || e > 164)) wild++;
    }
    unsigned long long m = __ballot(wild > 0);
    return (__popcll(m) >= 16) ? 1 : 0;
}

__device__ __forceinline__ float ldin(const void* p, int i, int fl) {
    return fl ? ((const float*)p)[i] : __bfloat162float(((const bf16*)p)[i]);
}

// vectorized dual-dtype loader: 4 consecutive elements at index i (i % 4 == 0)
__device__ __forceinline__ f4 ldin4(const void* p, int i, int fl) {
    if (fl) return *(const f4*)((const float*)p + i);
    ushort4 v = *(const ushort4*)((const unsigned short*)p + i);
    f4 r;
    r.x = __uint_as_float((unsigned)v.x << 16);
    r.y = __uint_as_float((unsigned)v.y << 16);
    r.z = __uint_as_float((unsigned)v.z << 16);
    r.w = __uint_as_float((unsigned)v.w << 16);
    return r;
}

// distributed convert: flat copies + 6 transposed weights ([O][K] -> [K][O]).
__device__ void convert_weights(const InPtrs& ptrs, int fl, float* ws, int bid) {
    int gidx = bid * 1024 + threadIdx.x;     // 0..262143
    const int fsrc[6] = {3, 4, 18, 20, 22, 2};
    const int fsz[6]  = {768, 128, 128, 128, 36, 4096};
    const int fdst[6] = {WEMBW, WEMBB, WB1, WB2, WBO, WPOS};
    #pragma unroll
    for (int s = 0; s < 6; s++) {
        const void* src = ptrs.p[fsrc[s]];
        float* dst = ws + fdst[s];
        for (int i = gidx; i < fsz[s]; i += 262144) dst[i] = ldin(src, i, fl);
    }
    const int tsrc[6] = {8, 12, 16, 17, 19, 21};
    const int tdst[6] = {WCP_T, WCSA_T, WCLA_T, W1_T, W2_T, WO_T};
    const int tO[6]   = {128, 128, 128, 128, 128, 36};
    #pragma unroll
    for (int s = 0; s < 6; s++) {
        const void* src = ptrs.p[tsrc[s]];
        float* dst = ws + tdst[s];
        int O = tO[s], n = O * 128;
        for (int j = gidx; j < n; j += 262144) {
            int k = j / O, o = j - k * O;
            dst[j] = ldin(src, o * 128 + k, fl);
        }
    }
}

// ---------------- K1: LaneAttentionPast (x = embedding), per (b,h) ----------------
__global__ __launch_bounds__(1024) void k1_lap(InPtrs ptrs, float* __restrict__ ws) {
    int bid = blockIdx.x, b = bid >> 3, h = bid & 7, t = threadIdx.x;
    int fl = detect_f32(ptrs.p[1], t);
    __shared__ __align__(16) float sm[27712];
    float* ln   = sm;            // 128*68 (aliased by scores later)
    float* xs   = sm + 8704;     // 64*132
    float* wql  = sm + 17152;    // 16*132
    float* wkl  = sm + 19264;    // 16*68
    float* wvl  = sm + 20352;    // 16*68
    float* kh   = sm + 21440;    // 128*20
    float* vhT  = sm + 24000;    // 16*132
    float* qh   = sm + 26112;    // 64*20
    float* rsum = sm + 27392;    // 64
    float* in4  = sm + 27456;    // 256
    float* s    = ln;
    float* osa  = ws + OFF_OSA1;

    convert_weights(ptrs, fl, ws, bid);

    // vectorized staging
    {
        int lb = b * NL * 64;
        for (int i = t * 4; i < NL * 64; i += 4096) {
            f4 w = ldin4(ptrs.p[1], lb + i, fl);
            *(f4*)&ln[(i >> 6) * 68 + (i & 63)] = w;
        }
        if (t < 512) {          // wq slice 16x128
            int i = t * 4;
            f4 w = ldin4(ptrs.p[5], h * 2048 + i, fl);
            *(f4*)&wql[(i >> 7) * 132 + (i & 127)] = w;
        } else if (t < 768) {   // wk slice 16x64
            int i = (t - 512) * 4;
            f4 w = ldin4(ptrs.p[6], h * 1024 + i, fl);
            *(f4*)&wkl[(i >> 6) * 68 + (i & 63)] = w;
        } else {                // wv slice 16x64
            int i = (t - 768) * 4;
            f4 w = ldin4(ptrs.p[7], h * 1024 + i, fl);
            *(f4*)&wvl[(i >> 6) * 68 + (i & 63)] = w;
        }
        if (t < 64) {
            in4[t * 4 + 0] = ldin(ptrs.p[0], ((b * 2 + 0) * 64 + t) * 20 + 18, fl);
            in4[t * 4 + 1] = ldin(ptrs.p[0], ((b * 2 + 0) * 64 + t) * 20 + 19, fl);
            in4[t * 4 + 2] = ldin(ptrs.p[0], ((b * 2 + 1) * 64 + t) * 20 + 18, fl);
            in4[t * 4 + 3] = ldin(ptrs.p[0], ((b * 2 + 1) * 64 + t) * 20 + 19, fl);
        }
    }
    __syncthreads();
    for (int i = t; i < 8192; i += 1024) {
        int v = i >> 7, c = i & 127;
        xs[v * 132 + c] = ldin(ptrs.p[4], c, fl)
            + in4[v * 4 + 0] * ldin(ptrs.p[3], c * 6 + 0, fl)
            + in4[v * 4 + 1] * ldin(ptrs.p[3], c * 6 + 1, fl)
            + in4[v * 4 + 2] * ldin(ptrs.p[3], c * 6 + 3, fl)
            + in4[v * 4 + 3] * ldin(ptrs.p[3], c * 6 + 4, fl);
    }
    __syncthreads();

    // proj: t<512 -> K,V (2l x 2d each); t>=512 -> Q (1v x 2d)
    if (t < 512) {
        int l0 = t & 63, d0 = (t >> 6) * 2;
        float ak[2][2] = {}, av[2][2] = {};
        for (int kk = 0; kk < 64; kk += 4) {
            f4 L[2], WK[2], WV[2];
            #pragma unroll
            for (int m = 0; m < 2; m++) L[m] = *(const f4*)&ln[(l0 + 64 * m) * 68 + kk];
            #pragma unroll
            for (int j = 0; j < 2; j++) {
                WK[j] = *(const f4*)&wkl[(d0 + j) * 68 + kk];
                WV[j] = *(const f4*)&wvl[(d0 + j) * 68 + kk];
            }
            #pragma unroll
            for (int m = 0; m < 2; m++)
                #pragma unroll
                for (int j = 0; j < 2; j++) {
                    ak[m][j] += dot4(L[m], WK[j]);
                    av[m][j] += dot4(L[m], WV[j]);
                }
        }
        #pragma unroll
        for (int m = 0; m < 2; m++)
            #pragma unroll
            for (int j = 0; j < 2; j++) {
                int l = l0 + 64 * m, d = d0 + j;
                kh[l * 20 + d] = ak[m][j];
                vhT[d * 132 + l] = av[m][j];
            }
    } else {
        int tt = t - 512, v = tt >> 3, d0 = (tt & 7) * 2;
        float aq[2] = {};
        for (int kk = 0; kk < 128; kk += 4) {
            f4 X = *(const f4*)&xs[v * 132 + kk];
            #pragma unroll
            for (int j = 0; j < 2; j++)
                aq[j] += dot4(X, *(const f4*)&wql[(d0 + j) * 132 + kk]);
        }
        #pragma unroll
        for (int j = 0; j < 2; j++) qh[v * 20 + d0 + j] = aq[j];
    }
    __syncthreads();

    {   // scores 64x128: 4v x 2l tiles -> s (dead ln)
        int v0 = t >> 6, l0 = t & 63;
        float sc[4][2] = {};
        #pragma unroll
        for (int kd = 0; kd < 16; kd += 4) {
            f4 Q[4], K2[2];
            #pragma unroll
            for (int m = 0; m < 4; m++) Q[m] = *(const f4*)&qh[(v0 + 16 * m) * 20 + kd];
            #pragma unroll
            for (int i2 = 0; i2 < 2; i2++) K2[i2] = *(const f4*)&kh[(l0 + 64 * i2) * 20 + kd];
            #pragma unroll
            for (int m = 0; m < 4; m++)
                #pragma unroll
                for (int i2 = 0; i2 < 2; i2++) sc[m][i2] += dot4(Q[m], K2[i2]);
        }
        #pragma unroll
        for (int m = 0; m < 4; m++)
            #pragma unroll
            for (int i2 = 0; i2 < 2; i2++)
                s[(v0 + 16 * m) * 132 + l0 + 64 * i2] = sc[m][i2] * 0.25f;
    }
    __syncthreads();

    {   // softmax over 128, 16 lanes/row
        int v = t >> 4, j = t & 15;
        float* sr = s + v * 132;
        float m = -1e30f;
        for (int k = j; k < NL; k += 16) m = fmaxf(m, sr[k]);
        for (int off = 1; off < 16; off <<= 1) m = fmaxf(m, __shfl_xor(m, off));
        float sum = 0.f;
        for (int k = j; k < NL; k += 16) { float e = __expf(sr[k] - m); sr[k] = e; sum += e; }
        for (int off = 1; off < 16; off <<= 1) sum += __shfl_xor(sum, off);
        if (j == 0) rsum[v] = sum;
    }
    __syncthreads();

    if (t < 512) {   // PV over 128: 1v x 2d
        int v = t >> 3, d0 = (t & 7) * 2;
        float o2[2] = {};
        for (int ll = 0; ll < NL; ll += 4) {
            f4 S4 = *(const f4*)&s[v * 132 + ll];
            #pragma unroll
            for (int j = 0; j < 2; j++)
                o2[j] += dot4(S4, *(const f4*)&vhT[(d0 + j) * 132 + ll]);
        }
        float* ob = osa + b * 8192 + h * 16;
        float inv = 1.0f / rsum[v];
        #pragma unroll
        for (int j = 0; j < 2; j++) ob[v * F + d0 + j] = o2[j] * inv;
    }
}

// ---------------- K2: feat1 = emb + osa1@wcP^T (in-block), SelfAttentionFut ----------------
__global__ __launch_bounds__(1024) void k2_saf(InPtrs ptrs, float* __restrict__ ws) {
    int bid = blockIdx.x, b = bid >> 3, h = bid & 7, t = threadIdx.x;
    int fl = detect_f32(ptrs.p[1], t);
    __shared__ __align__(16) float smem[23488];   // 94 KB
    float* osap = smem;            // 8448 (dead after feat1) -> qh/kh/vhT/s2/rsum
    float* qh   = smem;            // 1280
    float* kh   = smem + 1280;     // 1280
    float* vhT  = smem + 2560;     // 1088
    float* s2   = smem + 3648;     // 4352
    float* rsum = smem + 8000;     // 64
    float* xs   = smem + 8448;     // 8448
    float* wsl  = smem + 16896;    // 6336
    float* in4  = smem + 23232;    // 256

    const float* o1 = ws + OFF_OSA1 + b * 8192;
    for (int i = t * 4; i < 8192; i += 4096)
        *(f4*)&osap[(i >> 7) * 132 + (i & 127)] = *(const f4*)&o1[i];
    {
        int i = (t & 511) * 4;
        if (t < 512) {
            *(f4*)&wsl[(i >> 7) * 132 + (i & 127)] = ldin4(ptrs.p[10], h * 2048 + i, fl);
            *(f4*)&wsl[4224 + (i >> 7) * 132 + (i & 127)] = ldin4(ptrs.p[11], h * 2048 + i, fl);
        } else {
            *(f4*)&wsl[2112 + (i >> 7) * 132 + (i & 127)] = ldin4(ptrs.p[9], h * 2048 + i, fl);
        }
    }
    if (t < 64) {
        in4[t * 4 + 0] = ldin(ptrs.p[0], ((b * 2 + 0) * 64 + t) * 20 + 18, fl);
        in4[t * 4 + 1] = ldin(ptrs.p[0], ((b * 2 + 0) * 64 + t) * 20 + 19, fl);
        in4[t * 4 + 2] = ldin(ptrs.p[0], ((b * 2 + 1) * 64 + t) * 20 + 18, fl);
        in4[t * 4 + 3] = ldin(ptrs.p[0], ((b * 2 + 1) * 64 + t) * 20 + 19, fl);
    }
    __syncthreads();
    // emb into xs
    for (int i = t; i < 8192; i += 1024) {
        int v = i >> 7, c = i & 127;
        xs[v * 132 + c] = ws[WEMBB + c]
            + in4[v * 4 + 0] * ws[WEMBW + c * 6 + 0]
            + in4[v * 4 + 1] * ws[WEMBW + c * 6 + 1]
            + in4[v * 4 + 2] * ws[WEMBW + c * 6 + 3]
            + in4[v * 4 + 3] * ws[WEMBW + c * 6 + 4];
    }
    __syncthreads();
    // xs += osap @ wcpT  (transposed wcp [k][c]; 2v x 4c per thread)
    {
        const float* wT = ws + WCP_T;
        int v0 = (t >> 5) * 2, c0 = (t & 31) * 4;
        float acc[2][4];
        #pragma unroll
        for (int m = 0; m < 2; m++) {
            f4 X0 = *(const f4*)&xs[(v0 + m) * 132 + c0];
            acc[m][0] = X0.x; acc[m][1] = X0.y; acc[m][2] = X0.z; acc[m][3] = X0.w;
        }
        for (int k = 0; k < 128; k += 4) {
            f4 W0 = *(const f4*)&wT[(k + 0) * 128 + c0];
            f4 W1 = *(const f4*)&wT[(k + 1) * 128 + c0];
            f4 W2 = *(const f4*)&wT[(k + 2) * 128 + c0];
            f4 W3 = *(const f4*)&wT[(k + 3) * 128 + c0];
            #pragma unroll
            for (int m = 0; m < 2; m++) {
                f4 X = *(const f4*)&osap[(v0 + m) * 132 + k];
                acc[m][0] += X.x * W0.x + X.y * W1.x + X.z * W2.x + X.w * W3.x;
                acc[m][1] += X.x * W0.y + X.y * W1.y + X.z * W2.y + X.w * W3.y;
                acc[m][2] += X.x * W0.z + X.y * W1.z + X.z * W2.z + X.w * W3.z;
                acc[m][3] += X.x * W0.w + X.y * W1.w + X.z * W2.w + X.w * W3.w;
            }
        }
        #pragma unroll
        for (int m = 0; m < 2; m++)
            *(f4*)&xs[(v0 + m) * 132 + c0] =
                make_float4(acc[m][0], acc[m][1], acc[m][2], acc[m][3]);
    }
    __syncthreads();
    if (h == 0) {
        float* f1 = ws + OFF_FEAT1 + b * 8192;
        for (int i = t; i < 8192; i += 1024) f1[i] = xs[(i >> 7) * 132 + (i & 127)];
    }
    // NOTE: qh/kh/vhT alias osap — all osap reads completed before this sync
    __syncthreads();

    if (t < 512) {          // Q: 1v x 2d
        int v = t >> 3, d0 = (t & 7) * 2;
        float aq[2] = {};
        for (int kk = 0; kk < 128; kk += 4) {
            f4 X = *(const f4*)&xs[v * 132 + kk];
            #pragma unroll
            for (int j = 0; j < 2; j++)
                aq[j] += dot4(X, *(const f4*)&wsl[(d0 + j) * 132 + kk]);
        }
        #pragma unroll
        for (int j = 0; j < 2; j++) qh[v * 20 + d0 + j] = aq[j];
    } else if (t < 768) {   // K: 1v x 4d
        int tt = t - 512, v = tt >> 2, d0 = (tt & 3) * 4;
        float ak[4] = {};
        for (int kk = 0; kk < 128; kk += 4) {
            f4 X = *(const f4*)&xs[v * 132 + kk];
            #pragma unroll
            for (int j = 0; j < 4; j++)
                ak[j] += dot4(X, *(const f4*)&wsl[2112 + (d0 + j) * 132 + kk]);
        }
        #pragma unroll
        for (int j = 0; j < 4; j++) kh[v * 20 + d0 + j] = ak[j];
    } else {                // V -> transposed: 1v x 4d
        int tt = t - 768, v = tt >> 2, d0 = (tt & 3) * 4;
        float av[4] = {};
        for (int kk = 0; kk < 128; kk += 4) {
            f4 X = *(const f4*)&xs[v * 132 + kk];
            #pragma unroll
            for (int j = 0; j < 4; j++)
                av[j] += dot4(X, *(const f4*)&wsl[4224 + (d0 + j) * 132 + kk]);
        }
        #pragma unroll
        for (int j = 0; j < 4; j++) vhT[(d0 + j) * 68 + v] = av[j];
    }
    __syncthreads();

    {   // scores 64x64: 4v x 1l tiles
        int v0 = t >> 6, l = t & 63;
        float sc[4] = {};
        #pragma unroll
        for (int kd = 0; kd < 16; kd += 4) {
            f4 Kr = *(const f4*)&kh[l * 20 + kd];
            #pragma unroll
            for (int m = 0; m < 4; m++)
                sc[m] += dot4(*(const f4*)&qh[(v0 + 16 * m) * 20 + kd], Kr);
        }
        #pragma unroll
        for (int m = 0; m < 4; m++)
            s2[(v0 + 16 * m) * 68 + l] = sc[m] * 0.25f;
    }
    __syncthreads();

    {   // softmax over 64, 16 lanes/row
        int v = t >> 4, j = t & 15;
        float* sr = s2 + v * 68;
        float m = -1e30f;
        for (int k = j; k < V; k += 16) m = fmaxf(m, sr[k]);
        for (int off = 1; off < 16; off <<= 1) m = fmaxf(m, __shfl_xor(m, off));
        float sum = 0.f;
        for (int k = j; k < V; k += 16) { float e = __expf(sr[k] - m); sr[k] = e; sum += e; }
        for (int off = 1; off < 16; off <<= 1) sum += __shfl_xor(sum, off);
        if (j == 0) rsum[v] = sum;
    }
    __syncthreads();

    {   // PV: 1 output per thread (64v x 16d)
        int v = t >> 4, d = t & 15;
        float o = 0.f;
        for (int ll = 0; ll < V; ll += 4) {
            f4 S4 = *(const f4*)&s2[v * 68 + ll];
            o += dot4(S4, *(const f4*)&vhT[d * 68 + ll]);
        }
        float* ob = ws + OFF_OSA2 + b * 8192 + h * 16;
        ob[v * F + d] = o / rsum[v];
    }
}

// ---------------- K3: feat2 = feat1 + osa2@wcSA^T (in-block), LaneAttentionFut ----------------
__global__ __launch_bounds__(1024) void k3_laf(InPtrs ptrs, float* __restrict__ ws) {
    int bid = blockIdx.x, b = bid >> 3, h = bid & 7, t = threadIdx.x;
    int fl = detect_f32(ptrs.p[1], t);
    __shared__ __align__(16) float smem[29888];   // 119.5 KB
    float* ln   = smem;            // 8704 (scores alias)
    float* osas = smem + 8704;     // 8448 (dead after feat2) -> kh/vhT/qh/rsum
    float* kh   = smem + 8704;     // 2560
    float* vhT  = smem + 11264;    // 2112
    float* qh   = smem + 13376;    // 1280
    float* rsum = smem + 14656;    // 64
    float* xs   = smem + 17152;    // 8448
    float* wql  = smem + 25600;    // 2112
    float* wkl  = smem + 27712;    // 1088
    float* wvl  = smem + 28800;    // 1088
    float* s    = ln;

    {
        int lb = b * NL * 64;
        for (int i = t * 4; i < NL * 64; i += 4096) {
            f4 w = ldin4(ptrs.p[1], lb + i, fl);
            *(f4*)&ln[(i >> 6) * 68 + (i & 63)] = w;
        }
        const float* o2 = ws + OFF_OSA2 + b * 8192;
        for (int i = t * 4; i < 8192; i += 4096)
            *(f4*)&osas[(i >> 7) * 132 + (i & 127)] = *(const f4*)&o2[i];
        if (t < 512) {
            int i = t * 4;
            f4 w = ldin4(ptrs.p[15], h * 2048 + i, fl);
            *(f4*)&wql[(i >> 7) * 132 + (i & 127)] = w;
        } else if (t < 768) {
            int i = (t - 512) * 4;
            f4 w = ldin4(ptrs.p[13], h * 1024 + i, fl);
            *(f4*)&wkl[(i >> 6) * 68 + (i & 63)] = w;
        } else {
            int i = (t - 768) * 4;
            f4 w = ldin4(ptrs.p[14], h * 1024 + i, fl);
            *(f4*)&wvl[(i >> 6) * 68 + (i & 63)] = w;
        }
    }
    __syncthreads();
    // xs = feat1 + osas @ wcsaT  (2v x 4c)
    {
        const float* wT = ws + WCSA_T;
        const float* f1 = ws + OFF_FEAT1 + b * 8192;
        int v0 = (t >> 5) * 2, c0 = (t & 31) * 4;
        float acc[2][4];
        #pragma unroll
        for (int m = 0; m < 2; m++) {
            f4 X0 = *(const f4*)&f1[(v0 + m) * 128 + c0];
            acc[m][0] = X0.x; acc[m][1] = X0.y; acc[m][2] = X0.z; acc[m][3] = X0.w;
        }
        for (int k = 0; k < 128; k += 4) {
            f4 W0 = *(const f4*)&wT[(k + 0) * 128 + c0];
            f4 W1 = *(const f4*)&wT[(k + 1) * 128 + c0];
            f4 W2 = *(const f4*)&wT[(k + 2) * 128 + c0];
            f4 W3 = *(const f4*)&wT[(k + 3) * 128 + c0];
            #pragma unroll
            for (int m = 0; m < 2; m++) {
                f4 X = *(const f4*)&osas[(v0 + m) * 132 + k];
                acc[m][0] += X.x * W0.x + X.y * W1.x + X.z * W2.x + X.w * W3.x;
                acc[m][1] += X.x * W0.y + X.y * W1.y + X.z * W2.y + X.w * W3.y;
                acc[m][2] += X.x * W0.z + X.y * W1.z + X.z * W2.z + X.w * W3.z;
                acc[m][3] += X.x * W0.w + X.y * W1.w + X.z * W2.w + X.w * W3.w;
            }
        }
        #pragma unroll
        for (int m = 0; m < 2; m++)
            *(f4*)&xs[(v0 + m) * 132 + c0] =
                make_float4(acc[m][0], acc[m][1], acc[m][2], acc[m][3]);
    }
    __syncthreads();
    if (h == 0) {
        float* f2 = ws + OFF_FEAT2 + b * 8192;
        for (int i = t; i < 8192; i += 1024) f2[i] = xs[(i >> 7) * 132 + (i & 127)];
    }
    __syncthreads();   // osas reads done; kh/vhT/qh (alias) writes may begin

    // proj: t<512 -> K,V from lanes (2l x 2d); t>=512 -> Q from xs (1v x 2d)
    if (t < 512) {
        int l0 = t & 63, d0 = (t >> 6) * 2;
        float ak[2][2] = {}, av[2][2] = {};
        for (int kk = 0; kk < 64; kk += 4) {
            f4 L[2], WK[2], WV[2];
            #pragma unroll
            for (int m = 0; m < 2; m++) L[m] = *(const f4*)&ln[(l0 + 64 * m) * 68 + kk];
            #pragma unroll
            for (int j = 0; j < 2; j++) {
                WK[j] = *(const f4*)&wkl[(d0 + j) * 68 + kk];
                WV[j] = *(const f4*)&wvl[(d0 + j) * 68 + kk];
            }
            #pragma unroll
            for (int m = 0; m < 2; m++)
                #pragma unroll
                for (int j = 0; j < 2; j++) {
                    ak[m][j] += dot4(L[m], WK[j]);
                    av[m][j] += dot4(L[m], WV[j]);
                }
        }
        #pragma unroll
        for (int m = 0; m < 2; m++)
            #pragma unroll
            for (int j = 0; j < 2; j++) {
                int l = l0 + 64 * m, d = d0 + j;
                kh[l * 20 + d] = ak[m][j];
                vhT[d * 132 + l] = av[m][j];
            }
    } else {
        int tt = t - 512, v = tt >> 3, d0 = (tt & 7) * 2;
        float aq[2] = {};
        for (int kk = 0; kk < 128; kk += 4) {
            f4 X = *(const f4*)&xs[v * 132 + kk];
            #pragma unroll
            for (int j = 0; j < 2; j++)
                aq[j] += dot4(X, *(const f4*)&wql[(d0 + j) * 132 + kk]);
        }
        #pragma unroll
        for (int j = 0; j < 2; j++) qh[v * 20 + d0 + j] = aq[j];
    }
    __syncthreads();

    {   // scores 64x128: 4v x 2l
        int v0 = t >> 6, l0 = t & 63;
        float sc[4][2] = {};
        #pragma unroll
        for (int kd = 0; kd < 16; kd += 4) {
            f4 Q[4], K2[2];
            #pragma unroll
            for (int m = 0; m < 4; m++) Q[m] = *(const f4*)&qh[(v0 + 16 * m) * 20 + kd];
            #pragma unroll
            for (int i2 = 0; i2 < 2; i2++) K2[i2] = *(const f4*)&kh[(l0 + 64 * i2) * 20 + kd];
            #pragma unroll
            for (int m = 0; m < 4; m++)
                #pragma unroll
                for (int i2 = 0; i2 < 2; i2++) sc[m][i2] += dot4(Q[m], K2[i2]);
        }
        #pragma unroll
        for (int m = 0; m < 4; m++)
            #pragma unroll
            for (int i2 = 0; i2 < 2; i2++)
                s[(v0 + 16 * m) * 132 + l0 + 64 * i2] = sc[m][i2] * 0.25f;
    }
    __syncthreads();

    {   // softmax over 128, 16 lanes/row
        int v = t >> 4, j = t & 15;
        float* sr = s + v * 132;
        float m = -1e30f;
        for (int k = j; k < NL; k += 16) m = fmaxf(m, sr[k]);
        for (int off = 1; off < 16; off <<= 1) m = fmaxf(m, __shfl_xor(m, off));
        float sum = 0.f;
        for (int k = j; k < NL; k += 16) { float e = __expf(sr[k] - m); sr[k] = e; sum += e; }
        for (int off = 1; off < 16; off <<= 1) sum += __shfl_xor(sum, off);
        if (j == 0) rsum[v] = sum;
    }
    __syncthreads();

    if (t < 512) {   // PV over 128: 1v x 2d
        int v = t >> 3, d0 = (t & 7) * 2;
        float o2[2] = {};
        for (int ll = 0; ll < NL; ll += 4) {
            f4 S4 = *(const f4*)&s[v * 132 + ll];
            #pragma unroll
            for (int j = 0; j < 2; j++)
                o2[j] += dot4(S4, *(const f4*)&vhT[(d0 + j) * 132 + ll]);
        }
        float* ob = ws + OFF_OSA1 + b * 8192 + h * 16;   // osa1 dead, reuse
        float inv = 1.0f / rsum[v];
        #pragma unroll
        for (int j = 0; j < 2; j++) ob[v * F + d0 + j] = o2[j] * inv;
    }
}

// ---------------- K4: output head + activation + broadcast, 8 bv per block ----------------
__global__ __launch_bounds__(1024) void k4_out(InPtrs ptrs, float* __restrict__ ws,
                                               void* __restrict__ out) {
    int bid = blockIdx.x, t = threadIdx.x;
    int fl = detect_f32(ptrs.p[1], t);
    __shared__ __align__(16) float sm[4416];
    const float* ola  = ws + OFF_OSA1;
    const float* feat = ws + OFF_FEAT2;
    int bvl = t >> 7, u = t & 127;
    int bv = bid * 8 + bvl;
    float* orow = sm + bvl * 128;
    float* h3   = sm + 1024 + bvl * 128;
    float* z1   = sm + 2048 + bvl * 128;
    float* z2   = sm + 3072 + bvl * 128;
    float* z3all = sm + 4096;               // [8][40]
    float* z3   = z3all + bvl * 40;
    orow[u] = ola[bv * 128 + u];
    __syncthreads();
    const float* wclaT = ws + WCLA_T;
    float a0 = 0.f;
    for (int k = 0; k < 128; k++) a0 += orow[k] * wclaT[k * 128 + u];
    h3[u] = a0 + feat[bv * 128 + u];
    __syncthreads();
    const float* w1T = ws + W1_T;
    a0 = ws[WB1 + u];
    for (int k = 0; k < 128; k++) a0 += h3[k] * w1T[k * 128 + u];
    z1[u] = fmaxf(a0, 0.f);
    __syncthreads();
    const float* w2T = ws + W2_T;
    a0 = ws[WB2 + u];
    for (int k = 0; k < 128; k++) a0 += z1[k] * w2T[k * 128 + u];
    z2[u] = fmaxf(a0, 0.f);
    __syncthreads();
    const float* woT = ws + WO_T;
    if (u < 36) {
        float a = ws[WBO + u];
        for (int k = 0; k < 128; k++) a += z2[k] * woT[k * 36 + u];
        z3[u] = a;
    }
    __syncthreads();
    float r = 0.f;
    if (u < 36) {
        int c = u % 6;
        float xv = z3[u];
        if (c == 0)      r = xv + ws[WPOS + bv * 2 + 0];
        else if (c == 1) r = xv + ws[WPOS + bv * 2 + 1];
        else if (c == 2 || c == 3) r = __expf(0.5f * xv);
        else if (c == 4) r = tanhf(xv);
        else {
            const float inv = 0.4082482904638631f;  // 1/sqrt(6)
            float m = -1e30f;
            for (int pp = 0; pp < 6; pp++) m = fmaxf(m, z3[pp * 6 + 5] * inv);
            float sum = 0.f;
            for (int pp = 0; pp < 6; pp++) sum += __expf(z3[pp * 6 + 5] * inv - m);
            r = __expf(xv * inv - m) / sum;
        }
    }
    __syncthreads();
    if (u < 36) z3[u] = r;
    __syncthreads();
    int base = bid * 288;
    if (fl) {
        float* o = (float*)out;
        for (int i = t; i < LEN_PRED * 288; i += 1024) {
            int ttp = i / 288, idx = i - ttp * 288;
            o[ttp * 73728 + base + idx] = z3all[(idx / 36) * 40 + idx % 36];
        }
    } else {
        bf16* o = (bf16*)out;
        for (int i = t; i < LEN_PRED * 288; i += 1024) {
            int ttp = i / 288, idx = i - ttp * 288;
            o[ttp * 73728 + base + idx] = __float2bfloat16(z3all[(idx / 36) * 40 + idx % 36]);
        }
    }
}

extern "C" void kernel_launch(void* const* d_in, const int* in_sizes, int n_in,
                              void* d_out, int out_size, void* d_ws, size_t ws_size,
                              hipStream_t stream) {
    float* ws = (float*)d_ws;
    InPtrs ptrs;
    for (int i = 0; i < 23; i++) ptrs.p[i] = d_in[i];
    k1_lap<<<256, 1024, 0, stream>>>(ptrs, ws);
    k2_saf<<<256, 1024, 0, stream>>>(ptrs, ws);
    k3_laf<<<256, 1024, 0, stream>>>(ptrs, ws);
    k4_out<<<256, 1024, 0, stream>>>(ptrs, ws, d_out);
}

// Round 13
// 100.138 us; speedup vs baseline: 1.0497x; 1.0497x over previous
//
#include <hip/hip_runtime.h>
#include <hip/hip_bf16.h>
#include <math.h>

typedef __hip_bfloat16 bf16;
typedef float4 f4;

#define B 32
#define V 64
#define F 128
#define NL 128
#define H 8
#define DH 16
#define LEN_PRED 30

// ---- f32 workspace layout (element offsets) ----
#define WEMBW 0        // 768
#define WEMBB 768      // 128
#define WB1   896      // 128
#define WB2   1024     // 128
#define WBO   1152     // 36 (pad to 1192)
#define WPOS  1192     // 4096
// transposed [k][out]
#define WCP_T  5288    // 16384
#define WCSA_T 21672
#define WCLA_T 38056
#define W1_T   54440
#define W2_T   70824
#define WO_T   87208   // 4608 [k][36]
#define OFF_FEAT1 91904
#define OFF_FEAT2 354048
#define OFF_OSA1  616192
#define OFF_OSA2  878336

struct InPtrs { const void* p[23]; };

__device__ __forceinline__ float dot4(f4 a, f4 b) {
    return a.x * b.x + a.y * b.y + a.z * b.z + a.w * b.w;
}

// dtype detect: f32 read as u16 pairs has wild exponents in mantissa halves;
// bf16 N(0,1) never does. Uniform across all waves.
__device__ __forceinline__ int detect_f32(const void* lanesraw, int t) {
    const unsigned short* u = (const unsigned short*)lanesraw;
    int lane = t & 63;
    int wild = 0;
    for (int j = 0; j < 4; j++) {
        int e = (u[lane * 4 + j] >> 7) & 0xFF;
        if (e != 0 && (e < 90 || e > 164)) wild++;
    }
    unsigned long long m = __ballot(wild > 0);
    return (__popcll(m) >= 16) ? 1 : 0;
}

__device__ __forceinline__ float ldin(const void* p, int i, int fl) {
    return fl ? ((const float*)p)[i] : __bfloat162float(((const bf16*)p)[i]);
}

// vectorized dual-dtype loader: 4 consecutive elements at index i (i % 4 == 0)
__device__ __forceinline__ f4 ldin4(const void* p, int i, int fl) {
    if (fl) return *(const f4*)((const float*)p + i);
    ushort4 v = *(const ushort4*)((const unsigned short*)p + i);
    f4 r;
    r.x = __uint_as_float((unsigned)v.x << 16);
    r.y = __uint_as_float((unsigned)v.y << 16);
    r.z = __uint_as_float((unsigned)v.z << 16);
    r.w = __uint_as_float((unsigned)v.w << 16);
    return r;
}

// distributed convert: flat copies + 6 transposed weights ([O][K] -> [K][O]).
// Spread over all 256 blocks; <= ~1 element per thread. Runs at END of k1 so
// its scattered transpose reads don't delay k1's attention critical path.
__device__ void convert_weights(const InPtrs& ptrs, int fl, float* ws, int bid) {
    int gidx = bid * 512 + threadIdx.x;     // 0..131071
    const int fsrc[6] = {3, 4, 18, 20, 22, 2};
    const int fsz[6]  = {768, 128, 128, 128, 36, 4096};
    const int fdst[6] = {WEMBW, WEMBB, WB1, WB2, WBO, WPOS};
    #pragma unroll
    for (int s = 0; s < 6; s++) {
        const void* src = ptrs.p[fsrc[s]];
        float* dst = ws + fdst[s];
        for (int i = gidx; i < fsz[s]; i += 131072) dst[i] = ldin(src, i, fl);
    }
    const int tsrc[6] = {8, 12, 16, 17, 19, 21};
    const int tdst[6] = {WCP_T, WCSA_T, WCLA_T, W1_T, W2_T, WO_T};
    const int tO[6]   = {128, 128, 128, 128, 128, 36};
    #pragma unroll
    for (int s = 0; s < 6; s++) {
        const void* src = ptrs.p[tsrc[s]];
        float* dst = ws + tdst[s];
        int O = tO[s], n = O * 128;
        for (int j = gidx; j < n; j += 131072) {
            int k = j / O, o = j - k * O;
            dst[j] = ldin(src, o * 128 + k, fl);
        }
    }
}

// ---------------- K1: LaneAttentionPast (x = embedding), per (b,h) ----------------
__global__ __launch_bounds__(512) void k1_lap(InPtrs ptrs, float* __restrict__ ws) {
    int bid = blockIdx.x, b = bid >> 3, h = bid & 7, t = threadIdx.x;
    int fl = detect_f32(ptrs.p[1], t);
    __shared__ __align__(16) float sm[27712];
    float* ln   = sm;            // 128*68 (aliased by scores later)
    float* xs   = sm + 8704;     // 64*132
    float* wql  = sm + 17152;    // 16*132
    float* wkl  = sm + 19264;    // 16*68
    float* wvl  = sm + 20352;    // 16*68
    float* kh   = sm + 21440;    // 128*20
    float* vhT  = sm + 24000;    // 16*132
    float* qh   = sm + 26112;    // 64*20
    float* rsum = sm + 27392;    // 64
    float* in4  = sm + 27456;    // 256
    float* s    = ln;
    float* osa  = ws + OFF_OSA1;

    // vectorized staging
    {
        int lb = b * NL * 64;
        for (int i = t * 4; i < NL * 64; i += 2048) {
            f4 w = ldin4(ptrs.p[1], lb + i, fl);
            *(f4*)&ln[(i >> 6) * 68 + (i & 63)] = w;
        }
        {   // wq slice 16x128
            int i = t * 4;
            f4 w = ldin4(ptrs.p[5], h * 2048 + i, fl);
            *(f4*)&wql[(i >> 7) * 132 + (i & 127)] = w;
        }
        if (t < 256) {   // wk, wv slices 16x64
            int i = t * 4;
            f4 w = ldin4(ptrs.p[6], h * 1024 + i, fl);
            *(f4*)&wkl[(i >> 6) * 68 + (i & 63)] = w;
            w = ldin4(ptrs.p[7], h * 1024 + i, fl);
            *(f4*)&wvl[(i >> 6) * 68 + (i & 63)] = w;
        }
        if (t < 64) {
            in4[t * 4 + 0] = ldin(ptrs.p[0], ((b * 2 + 0) * 64 + t) * 20 + 18, fl);
            in4[t * 4 + 1] = ldin(ptrs.p[0], ((b * 2 + 0) * 64 + t) * 20 + 19, fl);
            in4[t * 4 + 2] = ldin(ptrs.p[0], ((b * 2 + 1) * 64 + t) * 20 + 18, fl);
            in4[t * 4 + 3] = ldin(ptrs.p[0], ((b * 2 + 1) * 64 + t) * 20 + 19, fl);
        }
    }
    __syncthreads();
    for (int i = t; i < 8192; i += 512) {
        int v = i >> 7, c = i & 127;
        xs[v * 132 + c] = ldin(ptrs.p[4], c, fl)
            + in4[v * 4 + 0] * ldin(ptrs.p[3], c * 6 + 0, fl)
            + in4[v * 4 + 1] * ldin(ptrs.p[3], c * 6 + 1, fl)
            + in4[v * 4 + 2] * ldin(ptrs.p[3], c * 6 + 3, fl)
            + in4[v * 4 + 3] * ldin(ptrs.p[3], c * 6 + 4, fl);
    }
    __syncthreads();

    // proj: t<256 -> K,V ; t>=256 -> Q
    if (t < 256) {
        int l0 = t >> 3, d0 = (t & 7) * 2;
        float ak[4][2] = {}, av[4][2] = {};
        for (int kk = 0; kk < 64; kk += 4) {
            f4 L[4], WK[2], WV[2];
            #pragma unroll
            for (int m = 0; m < 4; m++) L[m] = *(const f4*)&ln[(l0 + 32 * m) * 68 + kk];
            #pragma unroll
            for (int j = 0; j < 2; j++) {
                WK[j] = *(const f4*)&wkl[(d0 + j) * 68 + kk];
                WV[j] = *(const f4*)&wvl[(d0 + j) * 68 + kk];
            }
            #pragma unroll
            for (int m = 0; m < 4; m++)
                #pragma unroll
                for (int j = 0; j < 2; j++) {
                    ak[m][j] += dot4(L[m], WK[j]);
                    av[m][j] += dot4(L[m], WV[j]);
                }
        }
        #pragma unroll
        for (int m = 0; m < 4; m++)
            #pragma unroll
            for (int j = 0; j < 2; j++) {
                int l = l0 + 32 * m, d = d0 + j;
                kh[l * 20 + d] = ak[m][j];
                vhT[d * 132 + l] = av[m][j];
            }
    } else {
        int tt = t - 256, v = tt >> 2, d0 = (tt & 3) * 4;
        float aq[4] = {};
        for (int kk = 0; kk < 128; kk += 4) {
            f4 X = *(const f4*)&xs[v * 132 + kk];
            #pragma unroll
            for (int i2 = 0; i2 < 4; i2++)
                aq[i2] += dot4(X, *(const f4*)&wql[(d0 + i2) * 132 + kk]);
        }
        #pragma unroll
        for (int i2 = 0; i2 < 4; i2++) qh[v * 20 + d0 + i2] = aq[i2];
    }
    __syncthreads();

    {   // scores 64x128: 4x4 tiles -> s (dead ln)
        int v0 = t >> 5, l0 = t & 31;
        float sc[4][4] = {};
        #pragma unroll
        for (int kd = 0; kd < 16; kd += 4) {
            f4 Q[4], K4[4];
            #pragma unroll
            for (int m = 0; m < 4; m++) Q[m] = *(const f4*)&qh[(v0 + 16 * m) * 20 + kd];
            #pragma unroll
            for (int i2 = 0; i2 < 4; i2++) K4[i2] = *(const f4*)&kh[(l0 + 32 * i2) * 20 + kd];
            #pragma unroll
            for (int m = 0; m < 4; m++)
                #pragma unroll
                for (int i2 = 0; i2 < 4; i2++) sc[m][i2] += dot4(Q[m], K4[i2]);
        }
        #pragma unroll
        for (int m = 0; m < 4; m++)
            #pragma unroll
            for (int i2 = 0; i2 < 4; i2++)
                s[(v0 + 16 * m) * 132 + l0 + 32 * i2] = sc[m][i2] * 0.25f;
    }
    __syncthreads();

    {   // softmax over 128, 8 lanes/row
        int v = t >> 3, j = t & 7;
        float* sr = s + v * 132;
        float m = -1e30f;
        for (int k = j; k < NL; k += 8) m = fmaxf(m, sr[k]);
        for (int off = 1; off < 8; off <<= 1) m = fmaxf(m, __shfl_xor(m, off));
        float sum = 0.f;
        for (int k = j; k < NL; k += 8) { float e = __expf(sr[k] - m); sr[k] = e; sum += e; }
        for (int off = 1; off < 8; off <<= 1) sum += __shfl_xor(sum, off);
        if (j == 0) rsum[v] = sum;
    }
    __syncthreads();

    if (t < 256) {   // PV over 128
        int v = t >> 2, d0 = (t & 3) * 4;
        float o4[4] = {};
        for (int ll = 0; ll < NL; ll += 4) {
            f4 S4 = *(const f4*)&s[v * 132 + ll];
            #pragma unroll
            for (int i2 = 0; i2 < 4; i2++)
                o4[i2] += dot4(S4, *(const f4*)&vhT[(d0 + i2) * 132 + ll]);
        }
        float* ob = osa + b * 8192 + h * 16;
        float inv = 1.0f / rsum[v];
        #pragma unroll
        for (int i2 = 0; i2 < 4; i2++) ob[v * F + d0 + i2] = o4[i2] * inv;
    }

    // convert/transpose weights for k2..k4 — issued last, hidden in k1's tail
    convert_weights(ptrs, fl, ws, bid);
}

// ---------------- K2: feat1 = emb + osa1@wcP^T (in-block), SelfAttentionFut ----------------
__global__ __launch_bounds__(512) void k2_saf(InPtrs ptrs, float* __restrict__ ws) {
    int bid = blockIdx.x, b = bid >> 3, h = bid & 7, t = threadIdx.x;
    int fl = detect_f32(ptrs.p[1], t);
    __shared__ __align__(16) float smem[23488];   // 94 KB
    float* osap = smem;            // 8448 (dead after feat1) -> qh/kh/vhT/s2/rsum
    float* qh   = smem;            // 1280
    float* kh   = smem + 1280;     // 1280
    float* vhT  = smem + 2560;     // 1088
    float* s2   = smem + 3648;     // 4352
    float* rsum = smem + 8000;     // 64
    float* xs   = smem + 8448;     // 8448
    float* wsl  = smem + 16896;    // 6336
    float* in4  = smem + 23232;    // 256

    const float* o1 = ws + OFF_OSA1 + b * 8192;
    for (int i = t * 4; i < 8192; i += 2048)
        *(f4*)&osap[(i >> 7) * 132 + (i & 127)] = *(const f4*)&o1[i];
    {
        int i = t * 4;
        f4 w = ldin4(ptrs.p[10], h * 2048 + i, fl);
        *(f4*)&wsl[(i >> 7) * 132 + (i & 127)] = w;
        w = ldin4(ptrs.p[9], h * 2048 + i, fl);
        *(f4*)&wsl[2112 + (i >> 7) * 132 + (i & 127)] = w;
        w = ldin4(ptrs.p[11], h * 2048 + i, fl);
        *(f4*)&wsl[4224 + (i >> 7) * 132 + (i & 127)] = w;
    }
    if (t < 64) {
        in4[t * 4 + 0] = ldin(ptrs.p[0], ((b * 2 + 0) * 64 + t) * 20 + 18, fl);
        in4[t * 4 + 1] = ldin(ptrs.p[0], ((b * 2 + 0) * 64 + t) * 20 + 19, fl);
        in4[t * 4 + 2] = ldin(ptrs.p[0], ((b * 2 + 1) * 64 + t) * 20 + 18, fl);
        in4[t * 4 + 3] = ldin(ptrs.p[0], ((b * 2 + 1) * 64 + t) * 20 + 19, fl);
    }
    __syncthreads();
    // emb into xs (ws embw/embb are f32, converted in k1)
    for (int i = t; i < 8192; i += 512) {
        int v = i >> 7, c = i & 127;
        xs[v * 132 + c] = ws[WEMBB + c]
            + in4[v * 4 + 0] * ws[WEMBW + c * 6 + 0]
            + in4[v * 4 + 1] * ws[WEMBW + c * 6 + 1]
            + in4[v * 4 + 2] * ws[WEMBW + c * 6 + 3]
            + in4[v * 4 + 3] * ws[WEMBW + c * 6 + 4];
    }
    __syncthreads();
    // xs += osap @ wcpT  (transposed wcp [k][c]; coalesced column loads)
    {
        const float* wT = ws + WCP_T;
        int v0 = (t >> 5) * 4, c0 = (t & 31) * 4;
        float acc[4][4];
        #pragma unroll
        for (int m = 0; m < 4; m++) {
            f4 X0 = *(const f4*)&xs[(v0 + m) * 132 + c0];
            acc[m][0] = X0.x; acc[m][1] = X0.y; acc[m][2] = X0.z; acc[m][3] = X0.w;
        }
        for (int k = 0; k < 128; k += 4) {
            f4 W0 = *(const f4*)&wT[(k + 0) * 128 + c0];
            f4 W1 = *(const f4*)&wT[(k + 1) * 128 + c0];
            f4 W2 = *(const f4*)&wT[(k + 2) * 128 + c0];
            f4 W3 = *(const f4*)&wT[(k + 3) * 128 + c0];
            #pragma unroll
            for (int m = 0; m < 4; m++) {
                f4 X = *(const f4*)&osap[(v0 + m) * 132 + k];
                acc[m][0] += X.x * W0.x + X.y * W1.x + X.z * W2.x + X.w * W3.x;
                acc[m][1] += X.x * W0.y + X.y * W1.y + X.z * W2.y + X.w * W3.y;
                acc[m][2] += X.x * W0.z + X.y * W1.z + X.z * W2.z + X.w * W3.z;
                acc[m][3] += X.x * W0.w + X.y * W1.w + X.z * W2.w + X.w * W3.w;
            }
        }
        #pragma unroll
        for (int m = 0; m < 4; m++)
            *(f4*)&xs[(v0 + m) * 132 + c0] =
                make_float4(acc[m][0], acc[m][1], acc[m][2], acc[m][3]);
    }
    __syncthreads();
    if (h == 0) {
        float* f1 = ws + OFF_FEAT1 + b * 8192;
        for (int i = t; i < 8192; i += 512) f1[i] = xs[(i >> 7) * 132 + (i & 127)];
    }
    // NOTE: qh/kh/vhT alias osap — all osap reads completed before this sync
    __syncthreads();

    if (t < 256) {          // Q: 1v x 4d
        int v = t >> 2, d0 = (t & 3) * 4;
        float aq[4] = {};
        for (int kk = 0; kk < 128; kk += 4) {
            f4 X = *(const f4*)&xs[v * 132 + kk];
            #pragma unroll
            for (int i2 = 0; i2 < 4; i2++)
                aq[i2] += dot4(X, *(const f4*)&wsl[(d0 + i2) * 132 + kk]);
        }
        #pragma unroll
        for (int i2 = 0; i2 < 4; i2++) qh[v * 20 + d0 + i2] = aq[i2];
    } else if (t < 384) {   // K: 1v x 8d
        int tt = t - 256, v = tt >> 1, d0 = (tt & 1) * 8;
        float ak[8] = {};
        for (int kk = 0; kk < 128; kk += 4) {
            f4 X = *(const f4*)&xs[v * 132 + kk];
            #pragma unroll
            for (int i2 = 0; i2 < 8; i2++)
                ak[i2] += dot4(X, *(const f4*)&wsl[2112 + (d0 + i2) * 132 + kk]);
        }
        #pragma unroll
        for (int i2 = 0; i2 < 8; i2++) kh[v * 20 + d0 + i2] = ak[i2];
    } else {                // V -> transposed
        int tt = t - 384, v = tt >> 1, d0 = (tt & 1) * 8;
        float av[8] = {};
        for (int kk = 0; kk < 128; kk += 4) {
            f4 X = *(const f4*)&xs[v * 132 + kk];
            #pragma unroll
            for (int i2 = 0; i2 < 8; i2++)
                av[i2] += dot4(X, *(const f4*)&wsl[4224 + (d0 + i2) * 132 + kk]);
        }
        #pragma unroll
        for (int i2 = 0; i2 < 8; i2++) vhT[(d0 + i2) * 68 + v] = av[i2];
    }
    __syncthreads();

    {   // scores 64x64: 4x2 tiles
        int v0 = t >> 5, l0 = t & 31;
        float sc[4][2] = {};
        #pragma unroll
        for (int kd = 0; kd < 16; kd += 4) {
            f4 Q[4], K2[2];
            #pragma unroll
            for (int m = 0; m < 4; m++) Q[m] = *(const f4*)&qh[(v0 + 16 * m) * 20 + kd];
            #pragma unroll
            for (int i2 = 0; i2 < 2; i2++) K2[i2] = *(const f4*)&kh[(l0 + 32 * i2) * 20 + kd];
            #pragma unroll
            for (int m = 0; m < 4; m++)
                #pragma unroll
                for (int i2 = 0; i2 < 2; i2++) sc[m][i2] += dot4(Q[m], K2[i2]);
        }
        #pragma unroll
        for (int m = 0; m < 4; m++)
            #pragma unroll
            for (int i2 = 0; i2 < 2; i2++)
                s2[(v0 + 16 * m) * 68 + l0 + 32 * i2] = sc[m][i2] * 0.25f;
    }
    __syncthreads();

    {   // softmax over 64
        int v = t >> 3, j = t & 7;
        float* sr = s2 + v * 68;
        float m = -1e30f;
        for (int k = j; k < V; k += 8) m = fmaxf(m, sr[k]);
        for (int off = 1; off < 8; off <<= 1) m = fmaxf(m, __shfl_xor(m, off));
        float sum = 0.f;
        for (int k = j; k < V; k += 8) { float e = __expf(sr[k] - m); sr[k] = e; sum += e; }
        for (int off = 1; off < 8; off <<= 1) sum += __shfl_xor(sum, off);
        if (j == 0) rsum[v] = sum;
    }
    __syncthreads();

    if (t < 256) {          // PV
        int v = t >> 2, d0 = (t & 3) * 4;
        float o4[4] = {};
        for (int ll = 0; ll < V; ll += 4) {
            f4 S4 = *(const f4*)&s2[v * 68 + ll];
            #pragma unroll
            for (int i2 = 0; i2 < 4; i2++)
                o4[i2] += dot4(S4, *(const f4*)&vhT[(d0 + i2) * 68 + ll]);
        }
        float* ob = ws + OFF_OSA2 + b * 8192 + h * 16;
        float inv = 1.0f / rsum[v];
        #pragma unroll
        for (int i2 = 0; i2 < 4; i2++) ob[v * F + d0 + i2] = o4[i2] * inv;
    }
}

// ---------------- K3: feat2 = feat1 + osa2@wcSA^T (in-block), LaneAttentionFut ----------------
__global__ __launch_bounds__(512) void k3_laf(InPtrs ptrs, float* __restrict__ ws) {
    int bid = blockIdx.x, b = bid >> 3, h = bid & 7, t = threadIdx.x;
    int fl = detect_f32(ptrs.p[1], t);
    __shared__ __align__(16) float smem[29888];   // 119.5 KB
    float* ln   = smem;            // 8704 (scores alias)
    float* osas = smem + 8704;     // 8448 (dead after feat2) -> kh/vhT/qh/rsum
    float* kh   = smem + 8704;     // 2560
    float* vhT  = smem + 11264;    // 2112
    float* qh   = smem + 13376;    // 1280
    float* rsum = smem + 14656;    // 64
    float* xs   = smem + 17152;    // 8448
    float* wql  = smem + 25600;    // 2112
    float* wkl  = smem + 27712;    // 1088
    float* wvl  = smem + 28800;    // 1088
    float* s    = ln;

    {
        int lb = b * NL * 64;
        for (int i = t * 4; i < NL * 64; i += 2048) {
            f4 w = ldin4(ptrs.p[1], lb + i, fl);
            *(f4*)&ln[(i >> 6) * 68 + (i & 63)] = w;
        }
        const float* o2 = ws + OFF_OSA2 + b * 8192;
        for (int i = t * 4; i < 8192; i += 2048)
            *(f4*)&osas[(i >> 7) * 132 + (i & 127)] = *(const f4*)&o2[i];
        {
            int i = t * 4;
            f4 w = ldin4(ptrs.p[15], h * 2048 + i, fl);
            *(f4*)&wql[(i >> 7) * 132 + (i & 127)] = w;
        }
        if (t < 256) {
            int i = t * 4;
            f4 w = ldin4(ptrs.p[13], h * 1024 + i, fl);
            *(f4*)&wkl[(i >> 6) * 68 + (i & 63)] = w;
            w = ldin4(ptrs.p[14], h * 1024 + i, fl);
            *(f4*)&wvl[(i >> 6) * 68 + (i & 63)] = w;
        }
    }
    __syncthreads();
    // xs = feat1 + osas @ wcsaT  (transposed; coalesced column loads)
    {
        const float* wT = ws + WCSA_T;
        const float* f1 = ws + OFF_FEAT1 + b * 8192;
        int v0 = (t >> 5) * 4, c0 = (t & 31) * 4;
        float acc[4][4];
        #pragma unroll
        for (int m = 0; m < 4; m++) {
            f4 X0 = *(const f4*)&f1[(v0 + m) * 128 + c0];
            acc[m][0] = X0.x; acc[m][1] = X0.y; acc[m][2] = X0.z; acc[m][3] = X0.w;
        }
        for (int k = 0; k < 128; k += 4) {
            f4 W0 = *(const f4*)&wT[(k + 0) * 128 + c0];
            f4 W1 = *(const f4*)&wT[(k + 1) * 128 + c0];
            f4 W2 = *(const f4*)&wT[(k + 2) * 128 + c0];
            f4 W3 = *(const f4*)&wT[(k + 3) * 128 + c0];
            #pragma unroll
            for (int m = 0; m < 4; m++) {
                f4 X = *(const f4*)&osas[(v0 + m) * 132 + k];
                acc[m][0] += X.x * W0.x + X.y * W1.x + X.z * W2.x + X.w * W3.x;
                acc[m][1] += X.x * W0.y + X.y * W1.y + X.z * W2.y + X.w * W3.y;
                acc[m][2] += X.x * W0.z + X.y * W1.z + X.z * W2.z + X.w * W3.z;
                acc[m][3] += X.x * W0.w + X.y * W1.w + X.z * W2.w + X.w * W3.w;
            }
        }
        #pragma unroll
        for (int m = 0; m < 4; m++)
            *(f4*)&xs[(v0 + m) * 132 + c0] =
                make_float4(acc[m][0], acc[m][1], acc[m][2], acc[m][3]);
    }
    __syncthreads();
    if (h == 0) {
        float* f2 = ws + OFF_FEAT2 + b * 8192;
        for (int i = t; i < 8192; i += 512) f2[i] = xs[(i >> 7) * 132 + (i & 127)];
    }
    __syncthreads();   // osas reads done; kh/vhT/qh (alias) writes may begin

    // proj: t<256 -> K,V from lanes; t>=256 -> Q from xs
    if (t < 256) {
        int l0 = t >> 3, d0 = (t & 7) * 2;
        float ak[4][2] = {}, av[4][2] = {};
        for (int kk = 0; kk < 64; kk += 4) {
            f4 L[4], WK[2], WV[2];
            #pragma unroll
            for (int m = 0; m < 4; m++) L[m] = *(const f4*)&ln[(l0 + 32 * m) * 68 + kk];
            #pragma unroll
            for (int j = 0; j < 2; j++) {
                WK[j] = *(const f4*)&wkl[(d0 + j) * 68 + kk];
                WV[j] = *(const f4*)&wvl[(d0 + j) * 68 + kk];
            }
            #pragma unroll
            for (int m = 0; m < 4; m++)
                #pragma unroll
                for (int j = 0; j < 2; j++) {
                    ak[m][j] += dot4(L[m], WK[j]);
                    av[m][j] += dot4(L[m], WV[j]);
                }
        }
        #pragma unroll
        for (int m = 0; m < 4; m++)
            #pragma unroll
            for (int j = 0; j < 2; j++) {
                int l = l0 + 32 * m, d = d0 + j;
                kh[l * 20 + d] = ak[m][j];
                vhT[d * 132 + l] = av[m][j];
            }
    } else {
        int tt = t - 256, v = tt >> 2, d0 = (tt & 3) * 4;
        float aq[4] = {};
        for (int kk = 0; kk < 128; kk += 4) {
            f4 X = *(const f4*)&xs[v * 132 + kk];
            #pragma unroll
            for (int i2 = 0; i2 < 4; i2++)
                aq[i2] += dot4(X, *(const f4*)&wql[(d0 + i2) * 132 + kk]);
        }
        #pragma unroll
        for (int i2 = 0; i2 < 4; i2++) qh[v * 20 + d0 + i2] = aq[i2];
    }
    __syncthreads();

    {   // scores 64x128: 4x4 tiles -> s (dead ln)
        int v0 = t >> 5, l0 = t & 31;
        float sc[4][4] = {};
        #pragma unroll
        for (int kd = 0; kd < 16; kd += 4) {
            f4 Q[4], K4[4];
            #pragma unroll
            for (int m = 0; m < 4; m++) Q[m] = *(const f4*)&qh[(v0 + 16 * m) * 20 + kd];
            #pragma unroll
            for (int i2 = 0; i2 < 4; i2++) K4[i2] = *(const f4*)&kh[(l0 + 32 * i2) * 20 + kd];
            #pragma unroll
            for (int m = 0; m < 4; m++)
                #pragma unroll
                for (int i2 = 0; i2 < 4; i2++) sc[m][i2] += dot4(Q[m], K4[i2]);
        }
        #pragma unroll
        for (int m = 0; m < 4; m++)
            #pragma unroll
            for (int i2 = 0; i2 < 4; i2++)
                s[(v0 + 16 * m) * 132 + l0 + 32 * i2] = sc[m][i2] * 0.25f;
    }
    __syncthreads();

    {   // softmax over 128
        int v = t >> 3, j = t & 7;
        float* sr = s + v * 132;
        float m = -1e30f;
        for (int k = j; k < NL; k += 8) m = fmaxf(m, sr[k]);
        for (int off = 1; off < 8; off <<= 1) m = fmaxf(m, __shfl_xor(m, off));
        float sum = 0.f;
        for (int k = j; k < NL; k += 8) { float e = __expf(sr[k] - m); sr[k] = e; sum += e; }
        for (int off = 1; off < 8; off <<= 1) sum += __shfl_xor(sum, off);
        if (j == 0) rsum[v] = sum;
    }
    __syncthreads();

    if (t < 256) {   // PV over 128
        int v = t >> 2, d0 = (t & 3) * 4;
        float o4[4] = {};
        for (int ll = 0; ll < NL; ll += 4) {
            f4 S4 = *(const f4*)&s[v * 132 + ll];
            #pragma unroll
            for (int i2 = 0; i2 < 4; i2++)
                o4[i2] += dot4(S4, *(const f4*)&vhT[(d0 + i2) * 132 + ll]);
        }
        float* ob = ws + OFF_OSA1 + b * 8192 + h * 16;   // osa1 dead, reuse
        float inv = 1.0f / rsum[v];
        #pragma unroll
        for (int i2 = 0; i2 < 4; i2++) ob[v * F + d0 + i2] = o4[i2] * inv;
    }
}

// ---------------- K4: output head + activation + broadcast, 8 bv per block ----------------
__global__ __launch_bounds__(512) void k4_out(InPtrs ptrs, float* __restrict__ ws,
                                              void* __restrict__ out) {
    int bid = blockIdx.x, t = threadIdx.x;
    int fl = detect_f32(ptrs.p[1], t);
    __shared__ __align__(16) float sm[4416];
    const float* ola  = ws + OFF_OSA1;
    const float* feat = ws + OFF_FEAT2;
    int bvl = t >> 6, u = t & 63;
    int bv = bid * 8 + bvl;
    float* orow = sm + bvl * 128;
    float* h3   = sm + 1024 + bvl * 128;
    float* z1   = sm + 2048 + bvl * 128;
    float* z2   = sm + 3072 + bvl * 128;
    float* z3all = sm + 4096;               // [8][40]
    float* z3   = z3all + bvl * 40;
    orow[u] = ola[bv * 128 + u];
    orow[u + 64] = ola[bv * 128 + u + 64];
    __syncthreads();
    const float* wclaT = ws + WCLA_T;
    float a0 = 0.f, a1 = 0.f;
    for (int k = 0; k < 128; k++) {
        float x = orow[k];
        a0 += x * wclaT[k * 128 + u]; a1 += x * wclaT[k * 128 + u + 64];
    }
    h3[u] = a0 + feat[bv * 128 + u];
    h3[u + 64] = a1 + feat[bv * 128 + u + 64];
    __syncthreads();
    const float* w1T = ws + W1_T;
    a0 = ws[WB1 + u]; a1 = ws[WB1 + u + 64];
    for (int k = 0; k < 128; k++) {
        float x = h3[k];
        a0 += x * w1T[k * 128 + u]; a1 += x * w1T[k * 128 + u + 64];
    }
    z1[u] = fmaxf(a0, 0.f); z1[u + 64] = fmaxf(a1, 0.f);
    __syncthreads();
    const float* w2T = ws + W2_T;
    a0 = ws[WB2 + u]; a1 = ws[WB2 + u + 64];
    for (int k = 0; k < 128; k++) {
        float x = z1[k];
        a0 += x * w2T[k * 128 + u]; a1 += x * w2T[k * 128 + u + 64];
    }
    z2[u] = fmaxf(a0, 0.f); z2[u + 64] = fmaxf(a1, 0.f);
    __syncthreads();
    const float* woT = ws + WO_T;
    if (u < 36) {
        float a = ws[WBO + u];
        for (int k = 0; k < 128; k++) a += z2[k] * woT[k * 36 + u];
        z3[u] = a;
    }
    __syncthreads();
    float r = 0.f;
    if (u < 36) {
        int c = u % 6;
        float xv = z3[u];
        if (c == 0)      r = xv + ws[WPOS + bv * 2 + 0];
        else if (c == 1) r = xv + ws[WPOS + bv * 2 + 1];
        else if (c == 2 || c == 3) r = __expf(0.5f * xv);
        else if (c == 4) r = tanhf(xv);
        else {
            const float inv = 0.4082482904638631f;  // 1/sqrt(6)
            float m = -1e30f;
            for (int pp = 0; pp < 6; pp++) m = fmaxf(m, z3[pp * 6 + 5] * inv);
            float sum = 0.f;
            for (int pp = 0; pp < 6; pp++) sum += __expf(z3[pp * 6 + 5] * inv - m);
            r = __expf(xv * inv - m) / sum;
        }
    }
    __syncthreads();
    if (u < 36) z3[u] = r;
    __syncthreads();
    int base = bid * 288;
    if (fl) {
        float* o = (float*)out;
        for (int i = t; i < LEN_PRED * 288; i += 512) {
            int ttp = i / 288, idx = i - ttp * 288;
            o[ttp * 73728 + base + idx] = z3all[(idx / 36) * 40 + idx % 36];
        }
    } else {
        bf16* o = (bf16*)out;
        for (int i = t; i < LEN_PRED * 288; i += 512) {
            int ttp = i / 288, idx = i - ttp * 288;
            o[ttp * 73728 + base + idx] = __float2bfloat16(z3all[(idx / 36) * 40 + idx % 36]);
        }
    }
}

extern "C" void kernel_launch(void* const* d_in, const int* in_sizes, int n_in,
                              void* d_out, int out_size, void* d_ws, size_t ws_size,
                              hipStream_t stream) {
    float* ws = (float*)d_ws;
    InPtrs ptrs;
    for (int i = 0; i < 23; i++) ptrs.p[i] = d_in[i];
    k1_lap<<<256, 512, 0, stream>>>(ptrs, ws);
    k2_saf<<<256, 512, 0, stream>>>(ptrs, ws);
    k3_laf<<<256, 512, 0, stream>>>(ptrs, ws);
    k4_out<<<256, 512, 0, stream>>>(ptrs, ws, d_out);
}